// Round 9
// baseline (477.640 us; speedup 1.0000x reference)
//
#include <hip/hip_runtime.h>
#include <hip/hip_bf16.h>
#include <math.h>

#define LN_EPS 1e-5f

typedef __attribute__((ext_vector_type(8))) short short8;
typedef __attribute__((ext_vector_type(4))) float f32x4;
typedef unsigned short u16;
typedef unsigned int u32;

__device__ __forceinline__ u16 f2bf(float f) {
  __hip_bfloat16 h = __float2bfloat16(f);
  return __builtin_bit_cast(u16, h);
}
__device__ __forceinline__ float bf2f(u16 u) {
  u32 x = ((u32)u) << 16;
  return __builtin_bit_cast(float, x);
}

// ---------------- wave reduction helpers ----------------
__device__ __forceinline__ float wave_sum64(float v) {
#pragma unroll
  for (int m = 1; m <= 32; m <<= 1) v += __shfl_xor(v, m, 64);
  return v;
}
__device__ __forceinline__ float grp32_sum(float v) {
#pragma unroll
  for (int m = 1; m <= 16; m <<= 1) v += __shfl_xor(v, m, 64);
  return v;
}

// ---------------- extractor + QKV projection (R7-proven, byte-identical) ----------------
template <int DM>
__global__ __launch_bounds__(256) void extract_kernel(
    const float* __restrict__ xin, const float* __restrict__ lng,
    const float* __restrict__ lnb, const float* __restrict__ Wext,
    const float* __restrict__ bext, const float* __restrict__ Wq,
    const float* __restrict__ bq, const float* __restrict__ Wk,
    const float* __restrict__ bk, const float* __restrict__ Wv,
    const float* __restrict__ bv, float* __restrict__ featOut,
    u16* __restrict__ Qout, u16* __restrict__ Kout, u16* __restrict__ Vout) {
  __shared__ u16 sWq[4096], sWk[4096], sWv[4096];
  __shared__ float ybuf[4][256];
  __shared__ float fbuf[4][64];
  const int t = threadIdx.x, w = t >> 6, lane = t & 63;
  for (int i = t; i < 4096; i += 256) {
    sWq[i] = f2bf(Wq[i]);
    sWk[i] = f2bf(Wk[i]);
    sWv[i] = f2bf(Wv[i]);
  }
  __syncthreads();
#pragma unroll
  for (int rr = 0; rr < 2; ++rr) {
    const int r = blockIdx.x * 8 + rr * 4 + w;
    const float* x = xin + (size_t)r * DM;
    float xr[4];
    float s = 0.f, ss = 0.f;
#pragma unroll
    for (int u = 0; u < 4; ++u) {
      const int idx = u * 64 + lane;
      const float v = (idx < DM) ? x[idx] : 0.f;
      xr[u] = v;
      s += v;
      ss += v * v;
    }
    s = wave_sum64(s);
    ss = wave_sum64(ss);
    const float mean = s / (float)DM;
    const float rstd = rsqrtf(ss / (float)DM - mean * mean + LN_EPS);
#pragma unroll
    for (int u = 0; u < 4; ++u) {
      const int idx = u * 64 + lane;
      if (idx < DM) ybuf[w][idx] = (xr[u] - mean) * rstd * lng[idx] + lnb[idx];
    }
    __syncthreads();
    float acc = bext[lane];
#pragma unroll 8
    for (int i = 0; i < DM; ++i) acc += ybuf[w][i] * Wext[i * 64 + lane];
    const float f = fmaxf(acc, 0.f);
    featOut[(size_t)r * 64 + lane] = f;
    fbuf[w][lane] = f;
    __syncthreads();
    float aq = bq[lane], ak = bk[lane], av = bv[lane];
#pragma unroll 8
    for (int i = 0; i < 64; ++i) {
      const float fv = fbuf[w][i];
      aq += fv * bf2f(sWq[i * 64 + lane]);
      ak += fv * bf2f(sWk[i * 64 + lane]);
      av += fv * bf2f(sWv[i * 64 + lane]);
    }
    Qout[(size_t)r * 64 + lane] = f2bf(aq * 0.125f);  // fold 1/sqrt(64)
    Kout[(size_t)r * 64 + lane] = f2bf(ak);
    Vout[(size_t)r * 64 + lane] = f2bf(av);
    __syncthreads();
  }
}

// ---------------- flash attention, bf16 MFMA, 64 q/wave, 16 splits ----------------
// R9 bisect: R7-passing kernel + STRUCTURE (16 splits -> grid 1024 = 4
// blocks/CU; lds_p single-sub reuse with compiler fences; launch_bounds
// (256,4)) + ONE suspect under test: bf16 Opart. Softmax stays __expf and
// extract stays 0.125 (no exp2/QSCALE anywhere: that's the other suspect).
__global__ __launch_bounds__(256, 4) void attn_mfma_kernel(
    const u16* __restrict__ Qb0, const u16* __restrict__ Kb0,
    const u16* __restrict__ Vb0, const u16* __restrict__ Qb1,
    const u16* __restrict__ Kb1, const u16* __restrict__ Vb1,
    u16* __restrict__ Opart, float* __restrict__ lpart) {
  __shared__ __align__(16) u16 lds_k[4096];    // [kv][d] ^ ((kv&7)<<3)
  __shared__ __align__(16) u16 lds_vt[4096];   // [d][kv] ^ (((d>>1)&7)<<3)
  __shared__ __align__(16) u32 lds_p[4][544];  // per-wave [16 q][34], reused per sub

  const int bid = blockIdx.x;
  const int split = bid & 15;
  const int dir = (bid >> 4) & 1;
  const int qt = bid >> 5;
  const int slab = dir * 16 + split;
  const int kvbase = split * 512;

  const u16* Q = dir ? Qb1 : Qb0;
  const u16* K = dir ? Kb1 : Kb0;
  const u16* V = dir ? Vb1 : Vb0;

  const int t = threadIdx.x;
  const int w = t >> 6;
  const int lane = t & 63;
  const int g = lane >> 4;
  const int l16 = lane & 15;
  const int qblk = qt * 256 + w * 64;

  // ---- Q B-fragments: 4 q-subtiles x 2 k-chunks (pre-scaled by 1/8) ----
  short8 qa[4][2];
#pragma unroll
  for (int sub = 0; sub < 4; ++sub)
#pragma unroll
    for (int c = 0; c < 2; ++c)
      qa[sub][c] = *reinterpret_cast<const short8*>(
          Q + (size_t)(qblk + sub * 16 + l16) * 64 + 32 * c + 8 * g);

  f32x4 oacc[4][4];
#pragma unroll
  for (int sub = 0; sub < 4; ++sub)
#pragma unroll
    for (int db = 0; db < 4; ++db) oacc[sub][db] = f32x4{0.f, 0.f, 0.f, 0.f};
  float l_run[4] = {0.f, 0.f, 0.f, 0.f};

  const int kv0 = (t >> 4) << 2;
  const int d0 = (t & 15) << 2;
  ushort4 kh[4], vh[4];

#define LOADT(tile_)                                                          \
  {                                                                           \
    _Pragma("unroll") for (int j = 0; j < 4; ++j) {                           \
      const size_t off = ((size_t)(kvbase + (tile_)*64 + kv0 + j)) * 64 + d0; \
      kh[j] = *reinterpret_cast<const ushort4*>(K + off);                     \
      vh[j] = *reinterpret_cast<const ushort4*>(V + off);                     \
    }                                                                         \
  }

#define STORET()                                                              \
  {                                                                           \
    _Pragma("unroll") for (int j = 0; j < 4; ++j) {                           \
      const int row = kv0 + j;                                                \
      *reinterpret_cast<ushort4*>(                                            \
          &lds_k[(row * 64 + d0) ^ ((row & 7) << 3)]) = kh[j];                \
    }                                                                         \
    _Pragma("unroll") for (int i = 0; i < 4; ++i) {                           \
      const int row = d0 + i;                                                 \
      ushort4 vt;                                                             \
      vt.x = (&vh[0].x)[i];                                                   \
      vt.y = (&vh[1].x)[i];                                                   \
      vt.z = (&vh[2].x)[i];                                                   \
      vt.w = (&vh[3].x)[i];                                                   \
      *reinterpret_cast<ushort4*>(                                            \
          &lds_vt[(row * 64 + kv0) ^ (((row >> 1) & 7) << 3)]) = vt;          \
    }                                                                         \
  }

  LOADT(0);
  STORET();
  LOADT(1);
  asm volatile("s_waitcnt lgkmcnt(0)" ::: "memory");
  __builtin_amdgcn_s_barrier();
  asm volatile("" ::: "memory");

  for (int tile = 0; tile < 8; ++tile) {
    // ---- S^T = K Q for all 4 subs (K-fragment loaded once) ----
    f32x4 sacc[4][4];
#pragma unroll
    for (int sub = 0; sub < 4; ++sub)
#pragma unroll
      for (int kb = 0; kb < 4; ++kb) sacc[sub][kb] = f32x4{0.f, 0.f, 0.f, 0.f};
#pragma unroll
    for (int c = 0; c < 2; ++c) {
#pragma unroll
      for (int kb = 0; kb < 4; ++kb) {
        const int row = 16 * kb + l16;
        const int idx = (row * 64 + 32 * c + 8 * g) ^ ((row & 7) << 3);
        const short8 kfrag = *reinterpret_cast<const short8*>(&lds_k[idx]);
#pragma unroll
        for (int sub = 0; sub < 4; ++sub)
          sacc[sub][kb] = __builtin_amdgcn_mfma_f32_16x16x32_bf16(
              kfrag, qa[sub][c], sacc[sub][kb], 0, 0, 0);
      }
    }

    // ---- no-max softmax (__expf, R7-proven); per-sub P round-trip via
    //      reused per-wave buffer, fenced against compiler reordering ----
    short8 pB[4][2];
#pragma unroll
    for (int sub = 0; sub < 4; ++sub) {
      float lsub = 0.f;
#pragma unroll
      for (int kb = 0; kb < 4; ++kb) {
        const float p0 = __expf(sacc[sub][kb][0]);
        const float p1 = __expf(sacc[sub][kb][1]);
        const float p2 = __expf(sacc[sub][kb][2]);
        const float p3 = __expf(sacc[sub][kb][3]);
        lsub += (p0 + p1) + (p2 + p3);
        u32 w0, w1;
        asm("v_cvt_pk_bf16_f32 %0, %1, %2" : "=v"(w0) : "v"(p0), "v"(p1));
        asm("v_cvt_pk_bf16_f32 %0, %1, %2" : "=v"(w1) : "v"(p2), "v"(p3));
        *reinterpret_cast<uint2*>(&lds_p[w][l16 * 34 + 8 * kb + 2 * g]) =
            make_uint2(w0, w1);
      }
      l_run[sub] += lsub;
      asm volatile("" ::: "memory");  // writes before reads (in-wave DS order)
#pragma unroll
      for (int c = 0; c < 2; ++c) {
        const int base = l16 * 34 + 16 * c + 4 * g;
        const uint2 a = *reinterpret_cast<const uint2*>(&lds_p[w][base]);
        const uint2 bb = *reinterpret_cast<const uint2*>(&lds_p[w][base + 2]);
        u32 q4[4] = {a.x, a.y, bb.x, bb.y};
        pB[sub][c] = __builtin_bit_cast(short8, *(ulonglong2*)q4);
      }
      asm volatile("" ::: "memory");  // reads before next sub's overwrite
    }

    // ---- O^T += V^T P^T (V-fragment loaded once, shared by 4 subs) ----
#pragma unroll
    for (int c = 0; c < 2; ++c) {
#pragma unroll
      for (int db = 0; db < 4; ++db) {
        const int row = 16 * db + l16;
        const int idx = (row * 64 + 32 * c + 8 * g) ^ (((row >> 1) & 7) << 3);
        const short8 vfrag = *reinterpret_cast<const short8*>(&lds_vt[idx]);
#pragma unroll
        for (int sub = 0; sub < 4; ++sub)
          oacc[sub][db] = __builtin_amdgcn_mfma_f32_16x16x32_bf16(
              vfrag, pB[sub][c], oacc[sub][db], 0, 0, 0);
      }
    }

    // ---- rotate single K/V buffer ----
    asm volatile("s_waitcnt lgkmcnt(0)" ::: "memory");
    __builtin_amdgcn_s_barrier();
    asm volatile("" ::: "memory");
    if (tile < 7) {
      STORET();
      if (tile < 6) LOADT(tile + 2);
    }
    asm volatile("s_waitcnt lgkmcnt(0)" ::: "memory");
    __builtin_amdgcn_s_barrier();
    asm volatile("" ::: "memory");
  }

  // ---- epilogue: bf16 unnormalized O (suspect under test) + f32 l ----
  const size_t S = (size_t)8192 * 64;
#pragma unroll
  for (int sub = 0; sub < 4; ++sub) {
    const int q = qblk + sub * 16 + l16;
#pragma unroll
    for (int db = 0; db < 4; ++db) {
      u32 w0, w1;
      asm("v_cvt_pk_bf16_f32 %0, %1, %2"
          : "=v"(w0)
          : "v"(oacc[sub][db][0]), "v"(oacc[sub][db][1]));
      asm("v_cvt_pk_bf16_f32 %0, %1, %2"
          : "=v"(w1)
          : "v"(oacc[sub][db][2]), "v"(oacc[sub][db][3]));
      *reinterpret_cast<uint2*>(Opart + (size_t)slab * S + (size_t)q * 64 +
                                16 * db + 4 * g) = make_uint2(w0, w1);
    }
    float lv = l_run[sub];
    lv += __shfl_xor(lv, 16, 64);
    lv += __shfl_xor(lv, 32, 64);
    if (g == 0) lpart[slab * 8192 + q] = lv;
  }
#undef LOADT
#undef STORET
}

// ---------------- post (R7-proven; merge widened to 16 splits, bf16 Opart) ----------------
__global__ __launch_bounds__(256) void post_kernel(
    const u16* __restrict__ Opart, const float* __restrict__ lpart,
    const float* __restrict__ nirF, const float* __restrict__ libsF,
    const float* __restrict__ ln1g, const float* __restrict__ ln1b,
    const float* __restrict__ fc1w, const float* __restrict__ fc1b,
    const float* __restrict__ ln2g, const float* __restrict__ ln2b,
    const float* __restrict__ fc2w, const float* __restrict__ fc2b,
    const float* __restrict__ ln0g, const float* __restrict__ ln0b,
    const float* __restrict__ gatew, const float* __restrict__ gateb,
    const float* __restrict__ ln3g, const float* __restrict__ ln3b,
    const float* __restrict__ fc3w, const float* __restrict__ fc3b,
    const float* __restrict__ ln4g, const float* __restrict__ ln4b,
    const float* __restrict__ fc4w, const float* __restrict__ fc4b,
    float* __restrict__ out) {
  __shared__ u16 FC1[4096], FC2[4096], FC3[2048];
  __shared__ u16 GW[8192];
  __shared__ float rbuf[4][128];
  const int t = threadIdx.x, w = t >> 6, lane = t & 63;
  const size_t S = (size_t)8192 * 64;
  for (int i = t; i < 4096; i += 256) {
    FC1[i] = f2bf(fc1w[i]);
    FC2[i] = f2bf(fc2w[i]);
  }
  for (int i = t; i < 2048; i += 256) FC3[i] = f2bf(fc3w[i]);
  for (int i = t; i < 8192; i += 256) GW[i] = f2bf(gatew[i]);
  __syncthreads();
#pragma unroll
  for (int rr = 0; rr < 2; ++rr) {
    const int r = blockIdx.x * 8 + rr * 4 + w;
    const size_t ro = (size_t)r * 64;

    // merge 16 KV-splits per direction (no-max: plain sums), bf16 partials
    float a1 = 0.f, a2 = 0.f, l1 = 0.f, l2 = 0.f;
#pragma unroll
    for (int s = 0; s < 16; ++s) {
      a1 += bf2f(Opart[(size_t)s * S + ro + lane]);
      a2 += bf2f(Opart[(size_t)(16 + s) * S + ro + lane]);
      l1 += lpart[s * 8192 + r];
      l2 += lpart[(16 + s) * 8192 + r];
    }
    a1 /= l1;  // attn_libs_to_nir
    a2 /= l2;  // attn_nir_to_libs

    const float nv = nirF[ro + lane], lv_ = libsF[ro + lane];

    // out1 = relu(LN(a2; ln1) @ fc1 + b) + libs
    float s1 = wave_sum64(a2), ss1 = wave_sum64(a2 * a2);
    float mean = s1 * (1.f / 64);
    float rstd = rsqrtf(ss1 * (1.f / 64) - mean * mean + LN_EPS);
    rbuf[w][lane] = (a2 - mean) * rstd * ln1g[lane] + ln1b[lane];
    __syncthreads();
    float o1 = fc1b[lane];
#pragma unroll 8
    for (int i = 0; i < 64; ++i)
      o1 = fmaf(rbuf[w][i], bf2f(FC1[i * 64 + lane]), o1);
    const float out1 = fmaxf(o1, 0.f) + lv_;
    __syncthreads();

    // out2 = relu(LN(a1; ln2) @ fc2 + b) + nir
    s1 = wave_sum64(a1);
    ss1 = wave_sum64(a1 * a1);
    mean = s1 * (1.f / 64);
    rstd = rsqrtf(ss1 * (1.f / 64) - mean * mean + LN_EPS);
    rbuf[w][lane] = (a1 - mean) * rstd * ln2g[lane] + ln2b[lane];
    __syncthreads();
    float o2 = fc2b[lane];
#pragma unroll 8
    for (int i = 0; i < 64; ++i)
      o2 = fmaf(rbuf[w][i], bf2f(FC2[i * 64 + lane]), o2);
    const float out2 = fmaxf(o2, 0.f) + nv;
    __syncthreads();

    // gate
    s1 = wave_sum64(out1 + out2);
    ss1 = wave_sum64(out1 * out1 + out2 * out2);
    mean = s1 * (1.f / 128);
    rstd = rsqrtf(ss1 * (1.f / 128) - mean * mean + LN_EPS);
    rbuf[w][lane] = (out1 - mean) * rstd * ln0g[lane] + ln0b[lane];
    rbuf[w][64 + lane] =
        (out2 - mean) * rstd * ln0g[64 + lane] + ln0b[64 + lane];
    __syncthreads();
    float gg = gateb[lane];
#pragma unroll 8
    for (int i = 0; i < 128; ++i)
      gg = fmaf(rbuf[w][i], bf2f(GW[i * 64 + lane]), gg);
    gg = 1.f / (1.f + __expf(-gg));
    const float fused = gg * out1 + (1.f - gg) * out2;
    __syncthreads();

    // head: LN -> fc3 -> relu -> LN -> fc4
    s1 = wave_sum64(fused);
    ss1 = wave_sum64(fused * fused);
    mean = s1 * (1.f / 64);
    rstd = rsqrtf(ss1 * (1.f / 64) - mean * mean + LN_EPS);
    rbuf[w][lane] = (fused - mean) * rstd * ln3g[lane] + ln3b[lane];
    __syncthreads();
    if (lane < 32) {
      float h = fc3b[lane];
#pragma unroll 8
      for (int i = 0; i < 64; ++i)
        h = fmaf(rbuf[w][i], bf2f(FC3[i * 32 + lane]), h);
      h = fmaxf(h, 0.f);
      const float hs = grp32_sum(h), hss = grp32_sum(h * h);
      const float hm = hs * (1.f / 32);
      const float hr = rsqrtf(hss * (1.f / 32) - hm * hm + LN_EPS);
      const float y4 = (h - hm) * hr * ln4g[lane] + ln4b[lane];
      const float part = grp32_sum(y4 * fc4w[lane]);
      if (lane == 0) out[r] = part + fc4b[0];
    }
    __syncthreads();
  }
}

extern "C" void kernel_launch(void* const* d_in, const int* in_sizes, int n_in,
                              void* d_out, int out_size, void* d_ws,
                              size_t ws_size, hipStream_t stream) {
  const float* nir_data = (const float*)d_in[0];
  const float* libs_data = (const float*)d_in[1];
  const float* nir_ln_g = (const float*)d_in[2];
  const float* nir_ln_b = (const float*)d_in[3];
  const float* nir_w = (const float*)d_in[4];
  const float* nir_b = (const float*)d_in[5];
  const float* libs_ln_g = (const float*)d_in[6];
  const float* libs_ln_b = (const float*)d_in[7];
  const float* libs_w = (const float*)d_in[8];
  const float* libs_b = (const float*)d_in[9];
  const float* q_ln_w = (const float*)d_in[10];
  const float* q_ln_b = (const float*)d_in[11];
  const float* k_ln_w = (const float*)d_in[12];
  const float* k_ln_b = (const float*)d_in[13];
  const float* v_ln_w = (const float*)d_in[14];
  const float* v_ln_b = (const float*)d_in[15];
  const float* q_nl_w = (const float*)d_in[16];
  const float* q_nl_b = (const float*)d_in[17];
  const float* k_nl_w = (const float*)d_in[18];
  const float* k_nl_b = (const float*)d_in[19];
  const float* v_nl_w = (const float*)d_in[20];
  const float* v_nl_b = (const float*)d_in[21];
  const float* ln1_g = (const float*)d_in[22];
  const float* ln1_b = (const float*)d_in[23];
  const float* fc1_w = (const float*)d_in[24];
  const float* fc1_b = (const float*)d_in[25];
  const float* ln2_g = (const float*)d_in[26];
  const float* ln2_b = (const float*)d_in[27];
  const float* fc2_w = (const float*)d_in[28];
  const float* fc2_b = (const float*)d_in[29];
  const float* ln0_g = (const float*)d_in[30];
  const float* ln0_b = (const float*)d_in[31];
  const float* gate_w = (const float*)d_in[32];
  const float* gate_b = (const float*)d_in[33];
  const float* ln3_g = (const float*)d_in[34];
  const float* ln3_b = (const float*)d_in[35];
  const float* fc3_w = (const float*)d_in[36];
  const float* fc3_b = (const float*)d_in[37];
  const float* ln4_g = (const float*)d_in[38];
  const float* ln4_b = (const float*)d_in[39];
  const float* fc4_w = (const float*)d_in[40];
  const float* fc4_b = (const float*)d_in[41];

  const size_t S = (size_t)8192 * 64;
  u16* ub = (u16*)d_ws;
  u16* Qb_nir = ub + 0 * S;
  u16* Kb_nir = ub + 1 * S;
  u16* Vb_nir = ub + 2 * S;
  u16* Qb_libs = ub + 3 * S;
  u16* Kb_libs = ub + 4 * S;
  u16* Vb_libs = ub + 5 * S;
  u16* OpartU = ub + 6 * S;  // 32 slabs bf16 (2 dirs x 16 splits)
  float* fp = (float*)(ub + 38 * S);
  float* f_nir = fp + 0 * S;
  float* f_libs = fp + 1 * S;
  float* lpart = fp + 2 * S;  // 32 x 8192

  // nir: Q uses q_nl, K/V use *_ln
  extract_kernel<215><<<1024, 256, 0, stream>>>(
      nir_data, nir_ln_g, nir_ln_b, nir_w, nir_b, q_nl_w, q_nl_b, k_ln_w,
      k_ln_b, v_ln_w, v_ln_b, f_nir, Qb_nir, Kb_nir, Vb_nir);
  // libs: Q uses q_ln, K/V use *_nl
  extract_kernel<244><<<1024, 256, 0, stream>>>(
      libs_data, libs_ln_g, libs_ln_b, libs_w, libs_b, q_ln_w, q_ln_b, k_nl_w,
      k_nl_b, v_nl_w, v_nl_b, f_libs, Qb_libs, Kb_libs, Vb_libs);

  // dir0: Q_libs x K/V_nir ; dir1: Q_nir x K/V_libs
  attn_mfma_kernel<<<1024, 256, 0, stream>>>(Qb_libs, Kb_nir, Vb_nir, Qb_nir,
                                             Kb_libs, Vb_libs, OpartU, lpart);

  post_kernel<<<1024, 256, 0, stream>>>(
      OpartU, lpart, f_nir, f_libs, ln1_g, ln1_b, fc1_w, fc1_b, ln2_g, ln2_b,
      fc2_w, fc2_b, ln0_g, ln0_b, gate_w, gate_b, ln3_g, ln3_b, fc3_w, fc3_b,
      ln4_g, ln4_b, fc4_w, fc4_b, (float*)d_out);
}

// Round 10
// 161.975 us; speedup vs baseline: 2.9489x; 2.9489x over previous
//
#include <hip/hip_runtime.h>
#include <hip/hip_bf16.h>
#include <math.h>

#define LN_EPS 1e-5f

typedef __attribute__((ext_vector_type(8))) short short8;
typedef __attribute__((ext_vector_type(4))) float f32x4;
typedef unsigned short u16;
typedef unsigned int u32;

__device__ __forceinline__ u16 f2bf(float f) {
  __hip_bfloat16 h = __float2bfloat16(f);
  return __builtin_bit_cast(u16, h);
}
__device__ __forceinline__ float bf2f(u16 u) {
  u32 x = ((u32)u) << 16;
  return __builtin_bit_cast(float, x);
}

// ---------------- wave reduction helpers ----------------
__device__ __forceinline__ float wave_sum64(float v) {
#pragma unroll
  for (int m = 1; m <= 32; m <<= 1) v += __shfl_xor(v, m, 64);
  return v;
}
__device__ __forceinline__ float grp32_sum(float v) {
#pragma unroll
  for (int m = 1; m <= 16; m <<= 1) v += __shfl_xor(v, m, 64);
  return v;
}

// ---------------- extractor + QKV projection (R7/R9-proven, byte-identical) ----------------
template <int DM>
__global__ __launch_bounds__(256) void extract_kernel(
    const float* __restrict__ xin, const float* __restrict__ lng,
    const float* __restrict__ lnb, const float* __restrict__ Wext,
    const float* __restrict__ bext, const float* __restrict__ Wq,
    const float* __restrict__ bq, const float* __restrict__ Wk,
    const float* __restrict__ bk, const float* __restrict__ Wv,
    const float* __restrict__ bv, float* __restrict__ featOut,
    u16* __restrict__ Qout, u16* __restrict__ Kout, u16* __restrict__ Vout) {
  __shared__ u16 sWq[4096], sWk[4096], sWv[4096];
  __shared__ float ybuf[4][256];
  __shared__ float fbuf[4][64];
  const int t = threadIdx.x, w = t >> 6, lane = t & 63;
  for (int i = t; i < 4096; i += 256) {
    sWq[i] = f2bf(Wq[i]);
    sWk[i] = f2bf(Wk[i]);
    sWv[i] = f2bf(Wv[i]);
  }
  __syncthreads();
#pragma unroll
  for (int rr = 0; rr < 2; ++rr) {
    const int r = blockIdx.x * 8 + rr * 4 + w;
    const float* x = xin + (size_t)r * DM;
    float xr[4];
    float s = 0.f, ss = 0.f;
#pragma unroll
    for (int u = 0; u < 4; ++u) {
      const int idx = u * 64 + lane;
      const float v = (idx < DM) ? x[idx] : 0.f;
      xr[u] = v;
      s += v;
      ss += v * v;
    }
    s = wave_sum64(s);
    ss = wave_sum64(ss);
    const float mean = s / (float)DM;
    const float rstd = rsqrtf(ss / (float)DM - mean * mean + LN_EPS);
#pragma unroll
    for (int u = 0; u < 4; ++u) {
      const int idx = u * 64 + lane;
      if (idx < DM) ybuf[w][idx] = (xr[u] - mean) * rstd * lng[idx] + lnb[idx];
    }
    __syncthreads();
    float acc = bext[lane];
#pragma unroll 8
    for (int i = 0; i < DM; ++i) acc += ybuf[w][i] * Wext[i * 64 + lane];
    const float f = fmaxf(acc, 0.f);
    featOut[(size_t)r * 64 + lane] = f;
    fbuf[w][lane] = f;
    __syncthreads();
    float aq = bq[lane], ak = bk[lane], av = bv[lane];
#pragma unroll 8
    for (int i = 0; i < 64; ++i) {
      const float fv = fbuf[w][i];
      aq += fv * bf2f(sWq[i * 64 + lane]);
      ak += fv * bf2f(sWk[i * 64 + lane]);
      av += fv * bf2f(sWv[i * 64 + lane]);
    }
    Qout[(size_t)r * 64 + lane] = f2bf(aq * 0.125f);  // fold 1/sqrt(64)
    Kout[(size_t)r * 64 + lane] = f2bf(ak);
    Vout[(size_t)r * 64 + lane] = f2bf(av);
    __syncthreads();
  }
}

// ---------------- flash attention, bf16 MFMA, 32 q/wave, 16 splits ----------------
// R10: R9-proven kernel with wave state shrunk for real occupancy.
// 2 q-subtiles/wave (qa 16 + sacc 32 + oacc 32acc + staging 16 + pB 16
// ~= 130 regs total) -> fits 3 waves/SIMD; launch_bounds(256,3) (NEVER
// force a cap below natural allocation: R9's (256,4) caused 60-reg spill,
// 704MB scratch FETCH, 8x slowdown). grid 2048 = 64 qtiles x 2 dir x 16
// splits; 128 q/block. Softmax __expf (exp2/QSCALE convicted 3/3, banned).
__global__ __launch_bounds__(256, 3) void attn_mfma_kernel(
    const u16* __restrict__ Qb0, const u16* __restrict__ Kb0,
    const u16* __restrict__ Vb0, const u16* __restrict__ Qb1,
    const u16* __restrict__ Kb1, const u16* __restrict__ Vb1,
    u16* __restrict__ Opart, float* __restrict__ lpart) {
  __shared__ __align__(16) u16 lds_k[4096];    // [kv][d] ^ ((kv&7)<<3)
  __shared__ __align__(16) u16 lds_vt[4096];   // [d][kv] ^ (((d>>1)&7)<<3)
  __shared__ __align__(16) u32 lds_p[4][544];  // per-wave [16 q][34], reused per sub

  const int bid = blockIdx.x;
  const int split = bid & 15;
  const int dir = (bid >> 4) & 1;
  const int qt = bid >> 5;
  const int slab = dir * 16 + split;
  const int kvbase = split * 512;

  const u16* Q = dir ? Qb1 : Qb0;
  const u16* K = dir ? Kb1 : Kb0;
  const u16* V = dir ? Vb1 : Vb0;

  const int t = threadIdx.x;
  const int w = t >> 6;
  const int lane = t & 63;
  const int g = lane >> 4;
  const int l16 = lane & 15;
  const int qblk = qt * 128 + w * 32;

  // ---- Q B-fragments: 2 q-subtiles x 2 k-chunks (pre-scaled by 1/8) ----
  short8 qa[2][2];
#pragma unroll
  for (int sub = 0; sub < 2; ++sub)
#pragma unroll
    for (int c = 0; c < 2; ++c)
      qa[sub][c] = *reinterpret_cast<const short8*>(
          Q + (size_t)(qblk + sub * 16 + l16) * 64 + 32 * c + 8 * g);

  f32x4 oacc[2][4];
#pragma unroll
  for (int sub = 0; sub < 2; ++sub)
#pragma unroll
    for (int db = 0; db < 4; ++db) oacc[sub][db] = f32x4{0.f, 0.f, 0.f, 0.f};
  float l_run[2] = {0.f, 0.f};

  const int kv0 = (t >> 4) << 2;
  const int d0 = (t & 15) << 2;
  ushort4 kh[4], vh[4];

#define LOADT(tile_)                                                          \
  {                                                                           \
    _Pragma("unroll") for (int j = 0; j < 4; ++j) {                           \
      const size_t off = ((size_t)(kvbase + (tile_)*64 + kv0 + j)) * 64 + d0; \
      kh[j] = *reinterpret_cast<const ushort4*>(K + off);                     \
      vh[j] = *reinterpret_cast<const ushort4*>(V + off);                     \
    }                                                                         \
  }

#define STORET()                                                              \
  {                                                                           \
    _Pragma("unroll") for (int j = 0; j < 4; ++j) {                           \
      const int row = kv0 + j;                                                \
      *reinterpret_cast<ushort4*>(                                            \
          &lds_k[(row * 64 + d0) ^ ((row & 7) << 3)]) = kh[j];                \
    }                                                                         \
    _Pragma("unroll") for (int i = 0; i < 4; ++i) {                           \
      const int row = d0 + i;                                                 \
      ushort4 vt;                                                             \
      vt.x = (&vh[0].x)[i];                                                   \
      vt.y = (&vh[1].x)[i];                                                   \
      vt.z = (&vh[2].x)[i];                                                   \
      vt.w = (&vh[3].x)[i];                                                   \
      *reinterpret_cast<ushort4*>(                                            \
          &lds_vt[(row * 64 + kv0) ^ (((row >> 1) & 7) << 3)]) = vt;          \
    }                                                                         \
  }

  LOADT(0);
  STORET();
  LOADT(1);
  asm volatile("s_waitcnt lgkmcnt(0)" ::: "memory");
  __builtin_amdgcn_s_barrier();
  asm volatile("" ::: "memory");

  for (int tile = 0; tile < 8; ++tile) {
    // ---- S^T = K Q for both subs (K-fragment loaded once) ----
    f32x4 sacc[2][4];
#pragma unroll
    for (int sub = 0; sub < 2; ++sub)
#pragma unroll
      for (int kb = 0; kb < 4; ++kb) sacc[sub][kb] = f32x4{0.f, 0.f, 0.f, 0.f};
#pragma unroll
    for (int c = 0; c < 2; ++c) {
#pragma unroll
      for (int kb = 0; kb < 4; ++kb) {
        const int row = 16 * kb + l16;
        const int idx = (row * 64 + 32 * c + 8 * g) ^ ((row & 7) << 3);
        const short8 kfrag = *reinterpret_cast<const short8*>(&lds_k[idx]);
#pragma unroll
        for (int sub = 0; sub < 2; ++sub)
          sacc[sub][kb] = __builtin_amdgcn_mfma_f32_16x16x32_bf16(
              kfrag, qa[sub][c], sacc[sub][kb], 0, 0, 0);
      }
    }

    // ---- no-max softmax (__expf); per-sub P round-trip via reused buffer ----
    short8 pB[2][2];
#pragma unroll
    for (int sub = 0; sub < 2; ++sub) {
      float lsub = 0.f;
#pragma unroll
      for (int kb = 0; kb < 4; ++kb) {
        const float p0 = __expf(sacc[sub][kb][0]);
        const float p1 = __expf(sacc[sub][kb][1]);
        const float p2 = __expf(sacc[sub][kb][2]);
        const float p3 = __expf(sacc[sub][kb][3]);
        lsub += (p0 + p1) + (p2 + p3);
        u32 w0, w1;
        asm("v_cvt_pk_bf16_f32 %0, %1, %2" : "=v"(w0) : "v"(p0), "v"(p1));
        asm("v_cvt_pk_bf16_f32 %0, %1, %2" : "=v"(w1) : "v"(p2), "v"(p3));
        *reinterpret_cast<uint2*>(&lds_p[w][l16 * 34 + 8 * kb + 2 * g]) =
            make_uint2(w0, w1);
      }
      l_run[sub] += lsub;
      asm volatile("" ::: "memory");  // writes before reads (in-wave DS order)
#pragma unroll
      for (int c = 0; c < 2; ++c) {
        const int base = l16 * 34 + 16 * c + 4 * g;
        const uint2 a = *reinterpret_cast<const uint2*>(&lds_p[w][base]);
        const uint2 bb = *reinterpret_cast<const uint2*>(&lds_p[w][base + 2]);
        u32 q4[4] = {a.x, a.y, bb.x, bb.y};
        pB[sub][c] = __builtin_bit_cast(short8, *(ulonglong2*)q4);
      }
      asm volatile("" ::: "memory");  // reads before next sub's overwrite
    }

    // ---- O^T += V^T P^T (V-fragment loaded once, shared by both subs) ----
#pragma unroll
    for (int c = 0; c < 2; ++c) {
#pragma unroll
      for (int db = 0; db < 4; ++db) {
        const int row = 16 * db + l16;
        const int idx = (row * 64 + 32 * c + 8 * g) ^ (((row >> 1) & 7) << 3);
        const short8 vfrag = *reinterpret_cast<const short8*>(&lds_vt[idx]);
#pragma unroll
        for (int sub = 0; sub < 2; ++sub)
          oacc[sub][db] = __builtin_amdgcn_mfma_f32_16x16x32_bf16(
              vfrag, pB[sub][c], oacc[sub][db], 0, 0, 0);
      }
    }

    // ---- rotate single K/V buffer ----
    asm volatile("s_waitcnt lgkmcnt(0)" ::: "memory");
    __builtin_amdgcn_s_barrier();
    asm volatile("" ::: "memory");
    if (tile < 7) {
      STORET();
      if (tile < 6) LOADT(tile + 2);
    }
    asm volatile("s_waitcnt lgkmcnt(0)" ::: "memory");
    __builtin_amdgcn_s_barrier();
    asm volatile("" ::: "memory");
  }

  // ---- epilogue: bf16 unnormalized O + f32 l (R9-proven format) ----
  const size_t S = (size_t)8192 * 64;
#pragma unroll
  for (int sub = 0; sub < 2; ++sub) {
    const int q = qblk + sub * 16 + l16;
#pragma unroll
    for (int db = 0; db < 4; ++db) {
      u32 w0, w1;
      asm("v_cvt_pk_bf16_f32 %0, %1, %2"
          : "=v"(w0)
          : "v"(oacc[sub][db][0]), "v"(oacc[sub][db][1]));
      asm("v_cvt_pk_bf16_f32 %0, %1, %2"
          : "=v"(w1)
          : "v"(oacc[sub][db][2]), "v"(oacc[sub][db][3]));
      *reinterpret_cast<uint2*>(Opart + (size_t)slab * S + (size_t)q * 64 +
                                16 * db + 4 * g) = make_uint2(w0, w1);
    }
    float lv = l_run[sub];
    lv += __shfl_xor(lv, 16, 64);
    lv += __shfl_xor(lv, 32, 64);
    if (g == 0) lpart[slab * 8192 + q] = lv;
  }
#undef LOADT
#undef STORET
}

// ---------------- post (R9-proven, byte-identical) ----------------
__global__ __launch_bounds__(256) void post_kernel(
    const u16* __restrict__ Opart, const float* __restrict__ lpart,
    const float* __restrict__ nirF, const float* __restrict__ libsF,
    const float* __restrict__ ln1g, const float* __restrict__ ln1b,
    const float* __restrict__ fc1w, const float* __restrict__ fc1b,
    const float* __restrict__ ln2g, const float* __restrict__ ln2b,
    const float* __restrict__ fc2w, const float* __restrict__ fc2b,
    const float* __restrict__ ln0g, const float* __restrict__ ln0b,
    const float* __restrict__ gatew, const float* __restrict__ gateb,
    const float* __restrict__ ln3g, const float* __restrict__ ln3b,
    const float* __restrict__ fc3w, const float* __restrict__ fc3b,
    const float* __restrict__ ln4g, const float* __restrict__ ln4b,
    const float* __restrict__ fc4w, const float* __restrict__ fc4b,
    float* __restrict__ out) {
  __shared__ u16 FC1[4096], FC2[4096], FC3[2048];
  __shared__ u16 GW[8192];
  __shared__ float rbuf[4][128];
  const int t = threadIdx.x, w = t >> 6, lane = t & 63;
  const size_t S = (size_t)8192 * 64;
  for (int i = t; i < 4096; i += 256) {
    FC1[i] = f2bf(fc1w[i]);
    FC2[i] = f2bf(fc2w[i]);
  }
  for (int i = t; i < 2048; i += 256) FC3[i] = f2bf(fc3w[i]);
  for (int i = t; i < 8192; i += 256) GW[i] = f2bf(gatew[i]);
  __syncthreads();
#pragma unroll
  for (int rr = 0; rr < 2; ++rr) {
    const int r = blockIdx.x * 8 + rr * 4 + w;
    const size_t ro = (size_t)r * 64;

    // merge 16 KV-splits per direction (no-max: plain sums), bf16 partials
    float a1 = 0.f, a2 = 0.f, l1 = 0.f, l2 = 0.f;
#pragma unroll
    for (int s = 0; s < 16; ++s) {
      a1 += bf2f(Opart[(size_t)s * S + ro + lane]);
      a2 += bf2f(Opart[(size_t)(16 + s) * S + ro + lane]);
      l1 += lpart[s * 8192 + r];
      l2 += lpart[(16 + s) * 8192 + r];
    }
    a1 /= l1;  // attn_libs_to_nir
    a2 /= l2;  // attn_nir_to_libs

    const float nv = nirF[ro + lane], lv_ = libsF[ro + lane];

    // out1 = relu(LN(a2; ln1) @ fc1 + b) + libs
    float s1 = wave_sum64(a2), ss1 = wave_sum64(a2 * a2);
    float mean = s1 * (1.f / 64);
    float rstd = rsqrtf(ss1 * (1.f / 64) - mean * mean + LN_EPS);
    rbuf[w][lane] = (a2 - mean) * rstd * ln1g[lane] + ln1b[lane];
    __syncthreads();
    float o1 = fc1b[lane];
#pragma unroll 8
    for (int i = 0; i < 64; ++i)
      o1 = fmaf(rbuf[w][i], bf2f(FC1[i * 64 + lane]), o1);
    const float out1 = fmaxf(o1, 0.f) + lv_;
    __syncthreads();

    // out2 = relu(LN(a1; ln2) @ fc2 + b) + nir
    s1 = wave_sum64(a1);
    ss1 = wave_sum64(a1 * a1);
    mean = s1 * (1.f / 64);
    rstd = rsqrtf(ss1 * (1.f / 64) - mean * mean + LN_EPS);
    rbuf[w][lane] = (a1 - mean) * rstd * ln2g[lane] + ln2b[lane];
    __syncthreads();
    float o2 = fc2b[lane];
#pragma unroll 8
    for (int i = 0; i < 64; ++i)
      o2 = fmaf(rbuf[w][i], bf2f(FC2[i * 64 + lane]), o2);
    const float out2 = fmaxf(o2, 0.f) + nv;
    __syncthreads();

    // gate
    s1 = wave_sum64(out1 + out2);
    ss1 = wave_sum64(out1 * out1 + out2 * out2);
    mean = s1 * (1.f / 128);
    rstd = rsqrtf(ss1 * (1.f / 128) - mean * mean + LN_EPS);
    rbuf[w][lane] = (out1 - mean) * rstd * ln0g[lane] + ln0b[lane];
    rbuf[w][64 + lane] =
        (out2 - mean) * rstd * ln0g[64 + lane] + ln0b[64 + lane];
    __syncthreads();
    float gg = gateb[lane];
#pragma unroll 8
    for (int i = 0; i < 128; ++i)
      gg = fmaf(rbuf[w][i], bf2f(GW[i * 64 + lane]), gg);
    gg = 1.f / (1.f + __expf(-gg));
    const float fused = gg * out1 + (1.f - gg) * out2;
    __syncthreads();

    // head: LN -> fc3 -> relu -> LN -> fc4
    s1 = wave_sum64(fused);
    ss1 = wave_sum64(fused * fused);
    mean = s1 * (1.f / 64);
    rstd = rsqrtf(ss1 * (1.f / 64) - mean * mean + LN_EPS);
    rbuf[w][lane] = (fused - mean) * rstd * ln3g[lane] + ln3b[lane];
    __syncthreads();
    if (lane < 32) {
      float h = fc3b[lane];
#pragma unroll 8
      for (int i = 0; i < 64; ++i)
        h = fmaf(rbuf[w][i], bf2f(FC3[i * 32 + lane]), h);
      h = fmaxf(h, 0.f);
      const float hs = grp32_sum(h), hss = grp32_sum(h * h);
      const float hm = hs * (1.f / 32);
      const float hr = rsqrtf(hss * (1.f / 32) - hm * hm + LN_EPS);
      const float y4 = (h - hm) * hr * ln4g[lane] + ln4b[lane];
      const float part = grp32_sum(y4 * fc4w[lane]);
      if (lane == 0) out[r] = part + fc4b[0];
    }
    __syncthreads();
  }
}

extern "C" void kernel_launch(void* const* d_in, const int* in_sizes, int n_in,
                              void* d_out, int out_size, void* d_ws,
                              size_t ws_size, hipStream_t stream) {
  const float* nir_data = (const float*)d_in[0];
  const float* libs_data = (const float*)d_in[1];
  const float* nir_ln_g = (const float*)d_in[2];
  const float* nir_ln_b = (const float*)d_in[3];
  const float* nir_w = (const float*)d_in[4];
  const float* nir_b = (const float*)d_in[5];
  const float* libs_ln_g = (const float*)d_in[6];
  const float* libs_ln_b = (const float*)d_in[7];
  const float* libs_w = (const float*)d_in[8];
  const float* libs_b = (const float*)d_in[9];
  const float* q_ln_w = (const float*)d_in[10];
  const float* q_ln_b = (const float*)d_in[11];
  const float* k_ln_w = (const float*)d_in[12];
  const float* k_ln_b = (const float*)d_in[13];
  const float* v_ln_w = (const float*)d_in[14];
  const float* v_ln_b = (const float*)d_in[15];
  const float* q_nl_w = (const float*)d_in[16];
  const float* q_nl_b = (const float*)d_in[17];
  const float* k_nl_w = (const float*)d_in[18];
  const float* k_nl_b = (const float*)d_in[19];
  const float* v_nl_w = (const float*)d_in[20];
  const float* v_nl_b = (const float*)d_in[21];
  const float* ln1_g = (const float*)d_in[22];
  const float* ln1_b = (const float*)d_in[23];
  const float* fc1_w = (const float*)d_in[24];
  const float* fc1_b = (const float*)d_in[25];
  const float* ln2_g = (const float*)d_in[26];
  const float* ln2_b = (const float*)d_in[27];
  const float* fc2_w = (const float*)d_in[28];
  const float* fc2_b = (const float*)d_in[29];
  const float* ln0_g = (const float*)d_in[30];
  const float* ln0_b = (const float*)d_in[31];
  const float* gate_w = (const float*)d_in[32];
  const float* gate_b = (const float*)d_in[33];
  const float* ln3_g = (const float*)d_in[34];
  const float* ln3_b = (const float*)d_in[35];
  const float* fc3_w = (const float*)d_in[36];
  const float* fc3_b = (const float*)d_in[37];
  const float* ln4_g = (const float*)d_in[38];
  const float* ln4_b = (const float*)d_in[39];
  const float* fc4_w = (const float*)d_in[40];
  const float* fc4_b = (const float*)d_in[41];

  const size_t S = (size_t)8192 * 64;
  u16* ub = (u16*)d_ws;
  u16* Qb_nir = ub + 0 * S;
  u16* Kb_nir = ub + 1 * S;
  u16* Vb_nir = ub + 2 * S;
  u16* Qb_libs = ub + 3 * S;
  u16* Kb_libs = ub + 4 * S;
  u16* Vb_libs = ub + 5 * S;
  u16* OpartU = ub + 6 * S;  // 32 slabs bf16 (2 dirs x 16 splits)
  float* fp = (float*)(ub + 38 * S);
  float* f_nir = fp + 0 * S;
  float* f_libs = fp + 1 * S;
  float* lpart = fp + 2 * S;  // 32 x 8192

  // nir: Q uses q_nl, K/V use *_ln
  extract_kernel<215><<<1024, 256, 0, stream>>>(
      nir_data, nir_ln_g, nir_ln_b, nir_w, nir_b, q_nl_w, q_nl_b, k_ln_w,
      k_ln_b, v_ln_w, v_ln_b, f_nir, Qb_nir, Kb_nir, Vb_nir);
  // libs: Q uses q_ln, K/V use *_nl
  extract_kernel<244><<<1024, 256, 0, stream>>>(
      libs_data, libs_ln_g, libs_ln_b, libs_w, libs_b, q_ln_w, q_ln_b, k_nl_w,
      k_nl_b, v_nl_w, v_nl_b, f_libs, Qb_libs, Kb_libs, Vb_libs);

  // dir0: Q_libs x K/V_nir ; dir1: Q_nir x K/V_libs
  attn_mfma_kernel<<<2048, 256, 0, stream>>>(Qb_libs, Kb_nir, Vb_nir, Qb_nir,
                                             Kb_libs, Vb_libs, OpartU, lpart);

  post_kernel<<<1024, 256, 0, stream>>>(
      OpartU, lpart, f_nir, f_libs, ln1_g, ln1_b, fc1_w, fc1_b, ln2_g, ln2_b,
      fc2_w, fc2_b, ln0_g, ln0_b, gate_w, gate_b, ln3_g, ln3_b, fc3_w, fc3_b,
      ln4_g, ln4_b, fc4_w, fc4_b, (float*)d_out);
}

// Round 11
// 140.290 us; speedup vs baseline: 3.4047x; 1.1546x over previous
//
#include <hip/hip_runtime.h>
#include <hip/hip_bf16.h>
#include <math.h>

#define LN_EPS 1e-5f

typedef __attribute__((ext_vector_type(8))) short short8;
typedef __attribute__((ext_vector_type(4))) float f32x4;
typedef unsigned short u16;
typedef unsigned int u32;

__device__ __forceinline__ u16 f2bf(float f) {
  __hip_bfloat16 h = __float2bfloat16(f);
  return __builtin_bit_cast(u16, h);
}
__device__ __forceinline__ float bf2f(u16 u) {
  u32 x = ((u32)u) << 16;
  return __builtin_bit_cast(float, x);
}

// ---------------- wave reduction helpers ----------------
__device__ __forceinline__ float wave_sum64(float v) {
#pragma unroll
  for (int m = 1; m <= 32; m <<= 1) v += __shfl_xor(v, m, 64);
  return v;
}
__device__ __forceinline__ float grp32_sum(float v) {
#pragma unroll
  for (int m = 1; m <= 16; m <<= 1) v += __shfl_xor(v, m, 64);
  return v;
}

// ---------------- extractor + QKV projection ----------------
// R10-proven structure; only delta: 4-way split accumulators in the DM loop
// (breaks the 215-long serial FMA chain; tail loop avoids OOB Wext reads).
template <int DM>
__global__ __launch_bounds__(256) void extract_kernel(
    const float* __restrict__ xin, const float* __restrict__ lng,
    const float* __restrict__ lnb, const float* __restrict__ Wext,
    const float* __restrict__ bext, const float* __restrict__ Wq,
    const float* __restrict__ bq, const float* __restrict__ Wk,
    const float* __restrict__ bk, const float* __restrict__ Wv,
    const float* __restrict__ bv, float* __restrict__ featOut,
    u16* __restrict__ Qout, u16* __restrict__ Kout, u16* __restrict__ Vout) {
  __shared__ u16 sWq[4096], sWk[4096], sWv[4096];
  __shared__ float ybuf[4][256];
  __shared__ float fbuf[4][64];
  const int t = threadIdx.x, w = t >> 6, lane = t & 63;
  for (int i = t; i < 4096; i += 256) {
    sWq[i] = f2bf(Wq[i]);
    sWk[i] = f2bf(Wk[i]);
    sWv[i] = f2bf(Wv[i]);
  }
  __syncthreads();
#pragma unroll
  for (int rr = 0; rr < 2; ++rr) {
    const int r = blockIdx.x * 8 + rr * 4 + w;
    const float* x = xin + (size_t)r * DM;
    float xr[4];
    float s = 0.f, ss = 0.f;
#pragma unroll
    for (int u = 0; u < 4; ++u) {
      const int idx = u * 64 + lane;
      const float v = (idx < DM) ? x[idx] : 0.f;
      xr[u] = v;
      s += v;
      ss += v * v;
    }
    s = wave_sum64(s);
    ss = wave_sum64(ss);
    const float mean = s / (float)DM;
    const float rstd = rsqrtf(ss / (float)DM - mean * mean + LN_EPS);
#pragma unroll
    for (int u = 0; u < 4; ++u) {
      const int idx = u * 64 + lane;
      if (idx < DM) ybuf[w][idx] = (xr[u] - mean) * rstd * lng[idx] + lnb[idx];
    }
    __syncthreads();
    // 4-way split accumulators: cuts the serial FMA chain 4x
    float a0 = bext[lane], a1 = 0.f, a2 = 0.f, a3 = 0.f;
    int i = 0;
#pragma unroll 8
    for (; i + 4 <= DM; i += 4) {
      a0 = fmaf(ybuf[w][i + 0], Wext[(i + 0) * 64 + lane], a0);
      a1 = fmaf(ybuf[w][i + 1], Wext[(i + 1) * 64 + lane], a1);
      a2 = fmaf(ybuf[w][i + 2], Wext[(i + 2) * 64 + lane], a2);
      a3 = fmaf(ybuf[w][i + 3], Wext[(i + 3) * 64 + lane], a3);
    }
    for (; i < DM; ++i) a0 = fmaf(ybuf[w][i], Wext[i * 64 + lane], a0);
    const float f = fmaxf((a0 + a1) + (a2 + a3), 0.f);
    featOut[(size_t)r * 64 + lane] = f;
    fbuf[w][lane] = f;
    __syncthreads();
    float aq = bq[lane], ak = bk[lane], av = bv[lane];
#pragma unroll 8
    for (int j = 0; j < 64; ++j) {
      const float fv = fbuf[w][j];
      aq += fv * bf2f(sWq[j * 64 + lane]);
      ak += fv * bf2f(sWk[j * 64 + lane]);
      av += fv * bf2f(sWv[j * 64 + lane]);
    }
    Qout[(size_t)r * 64 + lane] = f2bf(aq * 0.125f);  // fold 1/sqrt(64)
    Kout[(size_t)r * 64 + lane] = f2bf(ak);
    Vout[(size_t)r * 64 + lane] = f2bf(av);
    __syncthreads();
  }
}

// ---------------- flash attention, bf16 MFMA, 64 q/wave, 16 splits ----------------
// R11 = recombination of proven pieces only:
//  - 4 q-subtiles/wave, 256 q/block (R7-proven fragment code, 52.5us)
//  - per-sub lds_p reuse with compiler fences (R9/R10-proven) -> LDS 24.7KB
//  - 16 splits x 512 kv, grid 1024 = 32 qtiles x 2 dir x 16 splits
//  - launch_bounds(256,2): NATURAL register allocation (R9: forced caps
//    below natural -> 60-reg spill, 8x slowdown. Never again.)
//  - __expf softmax (exp2/QSCALE convicted 3/3, banned); bf16 Opart (proven)
__global__ __launch_bounds__(256, 2) void attn_mfma_kernel(
    const u16* __restrict__ Qb0, const u16* __restrict__ Kb0,
    const u16* __restrict__ Vb0, const u16* __restrict__ Qb1,
    const u16* __restrict__ Kb1, const u16* __restrict__ Vb1,
    u16* __restrict__ Opart, float* __restrict__ lpart) {
  __shared__ __align__(16) u16 lds_k[4096];    // [kv][d] ^ ((kv&7)<<3)
  __shared__ __align__(16) u16 lds_vt[4096];   // [d][kv] ^ (((d>>1)&7)<<3)
  __shared__ __align__(16) u32 lds_p[4][544];  // per-wave [16 q][34], reused per sub

  const int bid = blockIdx.x;
  const int split = bid & 15;
  const int dir = (bid >> 4) & 1;
  const int qt = bid >> 5;
  const int slab = dir * 16 + split;
  const int kvbase = split * 512;

  const u16* Q = dir ? Qb1 : Qb0;
  const u16* K = dir ? Kb1 : Kb0;
  const u16* V = dir ? Vb1 : Vb0;

  const int t = threadIdx.x;
  const int w = t >> 6;
  const int lane = t & 63;
  const int g = lane >> 4;
  const int l16 = lane & 15;
  const int qblk = qt * 256 + w * 64;

  // ---- Q B-fragments: 4 q-subtiles x 2 k-chunks (pre-scaled by 1/8) ----
  short8 qa[4][2];
#pragma unroll
  for (int sub = 0; sub < 4; ++sub)
#pragma unroll
    for (int c = 0; c < 2; ++c)
      qa[sub][c] = *reinterpret_cast<const short8*>(
          Q + (size_t)(qblk + sub * 16 + l16) * 64 + 32 * c + 8 * g);

  f32x4 oacc[4][4];
#pragma unroll
  for (int sub = 0; sub < 4; ++sub)
#pragma unroll
    for (int db = 0; db < 4; ++db) oacc[sub][db] = f32x4{0.f, 0.f, 0.f, 0.f};
  float l_run[4] = {0.f, 0.f, 0.f, 0.f};

  const int kv0 = (t >> 4) << 2;
  const int d0 = (t & 15) << 2;
  ushort4 kh[4], vh[4];

#define LOADT(tile_)                                                          \
  {                                                                           \
    _Pragma("unroll") for (int j = 0; j < 4; ++j) {                           \
      const size_t off = ((size_t)(kvbase + (tile_)*64 + kv0 + j)) * 64 + d0; \
      kh[j] = *reinterpret_cast<const ushort4*>(K + off);                     \
      vh[j] = *reinterpret_cast<const ushort4*>(V + off);                     \
    }                                                                         \
  }

#define STORET()                                                              \
  {                                                                           \
    _Pragma("unroll") for (int j = 0; j < 4; ++j) {                           \
      const int row = kv0 + j;                                                \
      *reinterpret_cast<ushort4*>(                                            \
          &lds_k[(row * 64 + d0) ^ ((row & 7) << 3)]) = kh[j];                \
    }                                                                         \
    _Pragma("unroll") for (int i = 0; i < 4; ++i) {                           \
      const int row = d0 + i;                                                 \
      ushort4 vt;                                                             \
      vt.x = (&vh[0].x)[i];                                                   \
      vt.y = (&vh[1].x)[i];                                                   \
      vt.z = (&vh[2].x)[i];                                                   \
      vt.w = (&vh[3].x)[i];                                                   \
      *reinterpret_cast<ushort4*>(                                            \
          &lds_vt[(row * 64 + kv0) ^ (((row >> 1) & 7) << 3)]) = vt;          \
    }                                                                         \
  }

  LOADT(0);
  STORET();
  LOADT(1);
  asm volatile("s_waitcnt lgkmcnt(0)" ::: "memory");
  __builtin_amdgcn_s_barrier();
  asm volatile("" ::: "memory");

  for (int tile = 0; tile < 8; ++tile) {
    // ---- S^T = K Q for all 4 subs (K-fragment loaded once) ----
    f32x4 sacc[4][4];
#pragma unroll
    for (int sub = 0; sub < 4; ++sub)
#pragma unroll
      for (int kb = 0; kb < 4; ++kb) sacc[sub][kb] = f32x4{0.f, 0.f, 0.f, 0.f};
#pragma unroll
    for (int c = 0; c < 2; ++c) {
#pragma unroll
      for (int kb = 0; kb < 4; ++kb) {
        const int row = 16 * kb + l16;
        const int idx = (row * 64 + 32 * c + 8 * g) ^ ((row & 7) << 3);
        const short8 kfrag = *reinterpret_cast<const short8*>(&lds_k[idx]);
#pragma unroll
        for (int sub = 0; sub < 4; ++sub)
          sacc[sub][kb] = __builtin_amdgcn_mfma_f32_16x16x32_bf16(
              kfrag, qa[sub][c], sacc[sub][kb], 0, 0, 0);
      }
    }

    // ---- no-max softmax (__expf); per-sub P round-trip via reused buffer ----
    short8 pB[4][2];
#pragma unroll
    for (int sub = 0; sub < 4; ++sub) {
      float lsub = 0.f;
#pragma unroll
      for (int kb = 0; kb < 4; ++kb) {
        const float p0 = __expf(sacc[sub][kb][0]);
        const float p1 = __expf(sacc[sub][kb][1]);
        const float p2 = __expf(sacc[sub][kb][2]);
        const float p3 = __expf(sacc[sub][kb][3]);
        lsub += (p0 + p1) + (p2 + p3);
        u32 w0, w1;
        asm("v_cvt_pk_bf16_f32 %0, %1, %2" : "=v"(w0) : "v"(p0), "v"(p1));
        asm("v_cvt_pk_bf16_f32 %0, %1, %2" : "=v"(w1) : "v"(p2), "v"(p3));
        *reinterpret_cast<uint2*>(&lds_p[w][l16 * 34 + 8 * kb + 2 * g]) =
            make_uint2(w0, w1);
      }
      l_run[sub] += lsub;
      asm volatile("" ::: "memory");  // writes before reads (in-wave DS order)
#pragma unroll
      for (int c = 0; c < 2; ++c) {
        const int base = l16 * 34 + 16 * c + 4 * g;
        const uint2 a = *reinterpret_cast<const uint2*>(&lds_p[w][base]);
        const uint2 bb = *reinterpret_cast<const uint2*>(&lds_p[w][base + 2]);
        u32 q4[4] = {a.x, a.y, bb.x, bb.y};
        pB[sub][c] = __builtin_bit_cast(short8, *(ulonglong2*)q4);
      }
      asm volatile("" ::: "memory");  // reads before next sub's overwrite
    }

    // ---- O^T += V^T P^T (V-fragment loaded once, shared by 4 subs) ----
#pragma unroll
    for (int c = 0; c < 2; ++c) {
#pragma unroll
      for (int db = 0; db < 4; ++db) {
        const int row = 16 * db + l16;
        const int idx = (row * 64 + 32 * c + 8 * g) ^ (((row >> 1) & 7) << 3);
        const short8 vfrag = *reinterpret_cast<const short8*>(&lds_vt[idx]);
#pragma unroll
        for (int sub = 0; sub < 4; ++sub)
          oacc[sub][db] = __builtin_amdgcn_mfma_f32_16x16x32_bf16(
              vfrag, pB[sub][c], oacc[sub][db], 0, 0, 0);
      }
    }

    // ---- rotate single K/V buffer ----
    asm volatile("s_waitcnt lgkmcnt(0)" ::: "memory");
    __builtin_amdgcn_s_barrier();
    asm volatile("" ::: "memory");
    if (tile < 7) {
      STORET();
      if (tile < 6) LOADT(tile + 2);
    }
    asm volatile("s_waitcnt lgkmcnt(0)" ::: "memory");
    __builtin_amdgcn_s_barrier();
    asm volatile("" ::: "memory");
  }

  // ---- epilogue: bf16 unnormalized O + f32 l ----
  const size_t S = (size_t)8192 * 64;
#pragma unroll
  for (int sub = 0; sub < 4; ++sub) {
    const int q = qblk + sub * 16 + l16;
#pragma unroll
    for (int db = 0; db < 4; ++db) {
      u32 w0, w1;
      asm("v_cvt_pk_bf16_f32 %0, %1, %2"
          : "=v"(w0)
          : "v"(oacc[sub][db][0]), "v"(oacc[sub][db][1]));
      asm("v_cvt_pk_bf16_f32 %0, %1, %2"
          : "=v"(w1)
          : "v"(oacc[sub][db][2]), "v"(oacc[sub][db][3]));
      *reinterpret_cast<uint2*>(Opart + (size_t)slab * S + (size_t)q * 64 +
                                16 * db + 4 * g) = make_uint2(w0, w1);
    }
    float lv = l_run[sub];
    lv += __shfl_xor(lv, 16, 64);
    lv += __shfl_xor(lv, 32, 64);
    if (g == 0) lpart[slab * 8192 + q] = lv;
  }
#undef LOADT
#undef STORET
}

// ---------------- post (R9/R10-proven, byte-identical) ----------------
__global__ __launch_bounds__(256) void post_kernel(
    const u16* __restrict__ Opart, const float* __restrict__ lpart,
    const float* __restrict__ nirF, const float* __restrict__ libsF,
    const float* __restrict__ ln1g, const float* __restrict__ ln1b,
    const float* __restrict__ fc1w, const float* __restrict__ fc1b,
    const float* __restrict__ ln2g, const float* __restrict__ ln2b,
    const float* __restrict__ fc2w, const float* __restrict__ fc2b,
    const float* __restrict__ ln0g, const float* __restrict__ ln0b,
    const float* __restrict__ gatew, const float* __restrict__ gateb,
    const float* __restrict__ ln3g, const float* __restrict__ ln3b,
    const float* __restrict__ fc3w, const float* __restrict__ fc3b,
    const float* __restrict__ ln4g, const float* __restrict__ ln4b,
    const float* __restrict__ fc4w, const float* __restrict__ fc4b,
    float* __restrict__ out) {
  __shared__ u16 FC1[4096], FC2[4096], FC3[2048];
  __shared__ u16 GW[8192];
  __shared__ float rbuf[4][128];
  const int t = threadIdx.x, w = t >> 6, lane = t & 63;
  const size_t S = (size_t)8192 * 64;
  for (int i = t; i < 4096; i += 256) {
    FC1[i] = f2bf(fc1w[i]);
    FC2[i] = f2bf(fc2w[i]);
  }
  for (int i = t; i < 2048; i += 256) FC3[i] = f2bf(fc3w[i]);
  for (int i = t; i < 8192; i += 256) GW[i] = f2bf(gatew[i]);
  __syncthreads();
#pragma unroll
  for (int rr = 0; rr < 2; ++rr) {
    const int r = blockIdx.x * 8 + rr * 4 + w;
    const size_t ro = (size_t)r * 64;

    // merge 16 KV-splits per direction (no-max: plain sums), bf16 partials
    float a1 = 0.f, a2 = 0.f, l1 = 0.f, l2 = 0.f;
#pragma unroll
    for (int s = 0; s < 16; ++s) {
      a1 += bf2f(Opart[(size_t)s * S + ro + lane]);
      a2 += bf2f(Opart[(size_t)(16 + s) * S + ro + lane]);
      l1 += lpart[s * 8192 + r];
      l2 += lpart[(16 + s) * 8192 + r];
    }
    a1 /= l1;  // attn_libs_to_nir
    a2 /= l2;  // attn_nir_to_libs

    const float nv = nirF[ro + lane], lv_ = libsF[ro + lane];

    // out1 = relu(LN(a2; ln1) @ fc1 + b) + libs
    float s1 = wave_sum64(a2), ss1 = wave_sum64(a2 * a2);
    float mean = s1 * (1.f / 64);
    float rstd = rsqrtf(ss1 * (1.f / 64) - mean * mean + LN_EPS);
    rbuf[w][lane] = (a2 - mean) * rstd * ln1g[lane] + ln1b[lane];
    __syncthreads();
    float o1 = fc1b[lane];
#pragma unroll 8
    for (int i = 0; i < 64; ++i)
      o1 = fmaf(rbuf[w][i], bf2f(FC1[i * 64 + lane]), o1);
    const float out1 = fmaxf(o1, 0.f) + lv_;
    __syncthreads();

    // out2 = relu(LN(a1; ln2) @ fc2 + b) + nir
    s1 = wave_sum64(a1);
    ss1 = wave_sum64(a1 * a1);
    mean = s1 * (1.f / 64);
    rstd = rsqrtf(ss1 * (1.f / 64) - mean * mean + LN_EPS);
    rbuf[w][lane] = (a1 - mean) * rstd * ln2g[lane] + ln2b[lane];
    __syncthreads();
    float o2 = fc2b[lane];
#pragma unroll 8
    for (int i = 0; i < 64; ++i)
      o2 = fmaf(rbuf[w][i], bf2f(FC2[i * 64 + lane]), o2);
    const float out2 = fmaxf(o2, 0.f) + nv;
    __syncthreads();

    // gate
    s1 = wave_sum64(out1 + out2);
    ss1 = wave_sum64(out1 * out1 + out2 * out2);
    mean = s1 * (1.f / 128);
    rstd = rsqrtf(ss1 * (1.f / 128) - mean * mean + LN_EPS);
    rbuf[w][lane] = (out1 - mean) * rstd * ln0g[lane] + ln0b[lane];
    rbuf[w][64 + lane] =
        (out2 - mean) * rstd * ln0g[64 + lane] + ln0b[64 + lane];
    __syncthreads();
    float gg = gateb[lane];
#pragma unroll 8
    for (int i = 0; i < 128; ++i)
      gg = fmaf(rbuf[w][i], bf2f(GW[i * 64 + lane]), gg);
    gg = 1.f / (1.f + __expf(-gg));
    const float fused = gg * out1 + (1.f - gg) * out2;
    __syncthreads();

    // head: LN -> fc3 -> relu -> LN -> fc4
    s1 = wave_sum64(fused);
    ss1 = wave_sum64(fused * fused);
    mean = s1 * (1.f / 64);
    rstd = rsqrtf(ss1 * (1.f / 64) - mean * mean + LN_EPS);
    rbuf[w][lane] = (fused - mean) * rstd * ln3g[lane] + ln3b[lane];
    __syncthreads();
    if (lane < 32) {
      float h = fc3b[lane];
#pragma unroll 8
      for (int i = 0; i < 64; ++i)
        h = fmaf(rbuf[w][i], bf2f(FC3[i * 32 + lane]), h);
      h = fmaxf(h, 0.f);
      const float hs = grp32_sum(h), hss = grp32_sum(h * h);
      const float hm = hs * (1.f / 32);
      const float hr = rsqrtf(hss * (1.f / 32) - hm * hm + LN_EPS);
      const float y4 = (h - hm) * hr * ln4g[lane] + ln4b[lane];
      const float part = grp32_sum(y4 * fc4w[lane]);
      if (lane == 0) out[r] = part + fc4b[0];
    }
    __syncthreads();
  }
}

extern "C" void kernel_launch(void* const* d_in, const int* in_sizes, int n_in,
                              void* d_out, int out_size, void* d_ws,
                              size_t ws_size, hipStream_t stream) {
  const float* nir_data = (const float*)d_in[0];
  const float* libs_data = (const float*)d_in[1];
  const float* nir_ln_g = (const float*)d_in[2];
  const float* nir_ln_b = (const float*)d_in[3];
  const float* nir_w = (const float*)d_in[4];
  const float* nir_b = (const float*)d_in[5];
  const float* libs_ln_g = (const float*)d_in[6];
  const float* libs_ln_b = (const float*)d_in[7];
  const float* libs_w = (const float*)d_in[8];
  const float* libs_b = (const float*)d_in[9];
  const float* q_ln_w = (const float*)d_in[10];
  const float* q_ln_b = (const float*)d_in[11];
  const float* k_ln_w = (const float*)d_in[12];
  const float* k_ln_b = (const float*)d_in[13];
  const float* v_ln_w = (const float*)d_in[14];
  const float* v_ln_b = (const float*)d_in[15];
  const float* q_nl_w = (const float*)d_in[16];
  const float* q_nl_b = (const float*)d_in[17];
  const float* k_nl_w = (const float*)d_in[18];
  const float* k_nl_b = (const float*)d_in[19];
  const float* v_nl_w = (const float*)d_in[20];
  const float* v_nl_b = (const float*)d_in[21];
  const float* ln1_g = (const float*)d_in[22];
  const float* ln1_b = (const float*)d_in[23];
  const float* fc1_w = (const float*)d_in[24];
  const float* fc1_b = (const float*)d_in[25];
  const float* ln2_g = (const float*)d_in[26];
  const float* ln2_b = (const float*)d_in[27];
  const float* fc2_w = (const float*)d_in[28];
  const float* fc2_b = (const float*)d_in[29];
  const float* ln0_g = (const float*)d_in[30];
  const float* ln0_b = (const float*)d_in[31];
  const float* gate_w = (const float*)d_in[32];
  const float* gate_b = (const float*)d_in[33];
  const float* ln3_g = (const float*)d_in[34];
  const float* ln3_b = (const float*)d_in[35];
  const float* fc3_w = (const float*)d_in[36];
  const float* fc3_b = (const float*)d_in[37];
  const float* ln4_g = (const float*)d_in[38];
  const float* ln4_b = (const float*)d_in[39];
  const float* fc4_w = (const float*)d_in[40];
  const float* fc4_b = (const float*)d_in[41];

  const size_t S = (size_t)8192 * 64;
  u16* ub = (u16*)d_ws;
  u16* Qb_nir = ub + 0 * S;
  u16* Kb_nir = ub + 1 * S;
  u16* Vb_nir = ub + 2 * S;
  u16* Qb_libs = ub + 3 * S;
  u16* Kb_libs = ub + 4 * S;
  u16* Vb_libs = ub + 5 * S;
  u16* OpartU = ub + 6 * S;  // 32 slabs bf16 (2 dirs x 16 splits)
  float* fp = (float*)(ub + 38 * S);
  float* f_nir = fp + 0 * S;
  float* f_libs = fp + 1 * S;
  float* lpart = fp + 2 * S;  // 32 x 8192

  // nir: Q uses q_nl, K/V use *_ln
  extract_kernel<215><<<1024, 256, 0, stream>>>(
      nir_data, nir_ln_g, nir_ln_b, nir_w, nir_b, q_nl_w, q_nl_b, k_ln_w,
      k_ln_b, v_ln_w, v_ln_b, f_nir, Qb_nir, Kb_nir, Vb_nir);
  // libs: Q uses q_ln, K/V use *_nl
  extract_kernel<244><<<1024, 256, 0, stream>>>(
      libs_data, libs_ln_g, libs_ln_b, libs_w, libs_b, q_ln_w, q_ln_b, k_nl_w,
      k_nl_b, v_nl_w, v_nl_b, f_libs, Qb_libs, Kb_libs, Vb_libs);

  // dir0: Q_libs x K/V_nir ; dir1: Q_nir x K/V_libs
  attn_mfma_kernel<<<1024, 256, 0, stream>>>(Qb_libs, Kb_nir, Vb_nir, Qb_nir,
                                             Kb_libs, Vb_libs, OpartU, lpart);

  post_kernel<<<1024, 256, 0, stream>>>(
      OpartU, lpart, f_nir, f_libs, ln1_g, ln1_b, fc1_w, fc1_b, ln2_g, ln2_b,
      fc2_w, fc2_b, ln0_g, ln0_b, gate_w, gate_b, ln3_g, ln3_b, fc3_w, fc3_b,
      ln4_g, ln4_b, fc4_w, fc4_b, (float*)d_out);
}

// Round 12
// 128.392 us; speedup vs baseline: 3.7202x; 1.0927x over previous
//
#include <hip/hip_runtime.h>
#include <hip/hip_bf16.h>
#include <math.h>

#define LN_EPS 1e-5f

typedef __attribute__((ext_vector_type(8))) short short8;
typedef __attribute__((ext_vector_type(4))) float f32x4;
typedef unsigned short u16;
typedef unsigned int u32;

__device__ __forceinline__ u16 f2bf(float f) {
  __hip_bfloat16 h = __float2bfloat16(f);
  return __builtin_bit_cast(u16, h);
}
__device__ __forceinline__ float bf2f(u16 u) {
  u32 x = ((u32)u) << 16;
  return __builtin_bit_cast(float, x);
}

// ---------------- wave reduction helpers ----------------
__device__ __forceinline__ float wave_sum64(float v) {
#pragma unroll
  for (int m = 1; m <= 32; m <<= 1) v += __shfl_xor(v, m, 64);
  return v;
}
__device__ __forceinline__ float grp32_sum(float v) {
#pragma unroll
  for (int m = 1; m <= 16; m <<= 1) v += __shfl_xor(v, m, 64);
  return v;
}

// ---------------- extractor body (R11-proven, shared arrays passed in) ----------------
template <int DM>
__device__ __forceinline__ void extract_body(
    int bid, u16* sWq, u16* sWk, u16* sWv, float (*ybuf)[256],
    float (*fbuf)[64], const float* __restrict__ xin,
    const float* __restrict__ lng, const float* __restrict__ lnb,
    const float* __restrict__ Wext, const float* __restrict__ bext,
    const float* __restrict__ Wq, const float* __restrict__ bq,
    const float* __restrict__ Wk, const float* __restrict__ bk,
    const float* __restrict__ Wv, const float* __restrict__ bv,
    float* __restrict__ featOut, u16* __restrict__ Qout,
    u16* __restrict__ Kout, u16* __restrict__ Vout) {
  const int t = threadIdx.x, w = t >> 6, lane = t & 63;
  for (int i = t; i < 4096; i += 256) {
    sWq[i] = f2bf(Wq[i]);
    sWk[i] = f2bf(Wk[i]);
    sWv[i] = f2bf(Wv[i]);
  }
  __syncthreads();
#pragma unroll
  for (int rr = 0; rr < 2; ++rr) {
    const int r = bid * 8 + rr * 4 + w;
    const float* x = xin + (size_t)r * DM;
    float xr[4];
    float s = 0.f, ss = 0.f;
#pragma unroll
    for (int u = 0; u < 4; ++u) {
      const int idx = u * 64 + lane;
      const float v = (idx < DM) ? x[idx] : 0.f;
      xr[u] = v;
      s += v;
      ss += v * v;
    }
    s = wave_sum64(s);
    ss = wave_sum64(ss);
    const float mean = s / (float)DM;
    const float rstd = rsqrtf(ss / (float)DM - mean * mean + LN_EPS);
#pragma unroll
    for (int u = 0; u < 4; ++u) {
      const int idx = u * 64 + lane;
      if (idx < DM) ybuf[w][idx] = (xr[u] - mean) * rstd * lng[idx] + lnb[idx];
    }
    __syncthreads();
    // 4-way split accumulators: cuts the serial FMA chain 4x
    float a0 = bext[lane], a1 = 0.f, a2 = 0.f, a3 = 0.f;
    int i = 0;
#pragma unroll 8
    for (; i + 4 <= DM; i += 4) {
      a0 = fmaf(ybuf[w][i + 0], Wext[(i + 0) * 64 + lane], a0);
      a1 = fmaf(ybuf[w][i + 1], Wext[(i + 1) * 64 + lane], a1);
      a2 = fmaf(ybuf[w][i + 2], Wext[(i + 2) * 64 + lane], a2);
      a3 = fmaf(ybuf[w][i + 3], Wext[(i + 3) * 64 + lane], a3);
    }
    for (; i < DM; ++i) a0 = fmaf(ybuf[w][i], Wext[i * 64 + lane], a0);
    const float f = fmaxf((a0 + a1) + (a2 + a3), 0.f);
    featOut[(size_t)r * 64 + lane] = f;
    fbuf[w][lane] = f;
    __syncthreads();
    float aq = bq[lane], ak = bk[lane], av = bv[lane];
#pragma unroll 8
    for (int j = 0; j < 64; ++j) {
      const float fv = fbuf[w][j];
      aq += fv * bf2f(sWq[j * 64 + lane]);
      ak += fv * bf2f(sWk[j * 64 + lane]);
      av += fv * bf2f(sWv[j * 64 + lane]);
    }
    Qout[(size_t)r * 64 + lane] = f2bf(aq * 0.125f);  // fold 1/sqrt(64)
    Kout[(size_t)r * 64 + lane] = f2bf(ak);
    Vout[(size_t)r * 64 + lane] = f2bf(av);
    __syncthreads();
  }
}

// ---------------- fused extractor: blocks [0,1024) nir, [1024,2048) libs ----------------
__global__ __launch_bounds__(256) void extract_fused_kernel(
    const float* __restrict__ nir_x, const float* __restrict__ libs_x,
    const float* __restrict__ n_lng, const float* __restrict__ n_lnb,
    const float* __restrict__ n_We, const float* __restrict__ n_be,
    const float* __restrict__ l_lng, const float* __restrict__ l_lnb,
    const float* __restrict__ l_We, const float* __restrict__ l_be,
    const float* __restrict__ q_ln_w, const float* __restrict__ q_ln_b,
    const float* __restrict__ k_ln_w, const float* __restrict__ k_ln_b,
    const float* __restrict__ v_ln_w, const float* __restrict__ v_ln_b,
    const float* __restrict__ q_nl_w, const float* __restrict__ q_nl_b,
    const float* __restrict__ k_nl_w, const float* __restrict__ k_nl_b,
    const float* __restrict__ v_nl_w, const float* __restrict__ v_nl_b,
    float* __restrict__ f_nir, float* __restrict__ f_libs,
    u16* __restrict__ Qb_nir, u16* __restrict__ Kb_nir,
    u16* __restrict__ Vb_nir, u16* __restrict__ Qb_libs,
    u16* __restrict__ Kb_libs, u16* __restrict__ Vb_libs) {
  __shared__ u16 sWq[4096], sWk[4096], sWv[4096];
  __shared__ float ybuf[4][256];
  __shared__ float fbuf[4][64];
  if (blockIdx.x < 1024) {
    // nir: Q uses q_nl, K/V use *_ln
    extract_body<215>(blockIdx.x, sWq, sWk, sWv, ybuf, fbuf, nir_x, n_lng,
                      n_lnb, n_We, n_be, q_nl_w, q_nl_b, k_ln_w, k_ln_b,
                      v_ln_w, v_ln_b, f_nir, Qb_nir, Kb_nir, Vb_nir);
  } else {
    // libs: Q uses q_ln, K/V use *_nl
    extract_body<244>(blockIdx.x - 1024, sWq, sWk, sWv, ybuf, fbuf, libs_x,
                      l_lng, l_lnb, l_We, l_be, q_ln_w, q_ln_b, k_nl_w,
                      k_nl_b, v_nl_w, v_nl_b, f_libs, Qb_libs, Kb_libs,
                      Vb_libs);
  }
}

// ---------------- flash attention, bf16 MFMA, 64 q/wave, 8 splits ----------------
// R12 = R11 body with R7's split config (8 splits x 1024 kv, grid 512 =
// exactly the 2-block/CU VGPR-limited residency -> one block-round per CU,
// no tail; 16 tiles/block). Opart halves to 16 slabs.
__global__ __launch_bounds__(256, 2) void attn_mfma_kernel(
    const u16* __restrict__ Qb0, const u16* __restrict__ Kb0,
    const u16* __restrict__ Vb0, const u16* __restrict__ Qb1,
    const u16* __restrict__ Kb1, const u16* __restrict__ Vb1,
    u16* __restrict__ Opart, float* __restrict__ lpart) {
  __shared__ __align__(16) u16 lds_k[4096];    // [kv][d] ^ ((kv&7)<<3)
  __shared__ __align__(16) u16 lds_vt[4096];   // [d][kv] ^ (((d>>1)&7)<<3)
  __shared__ __align__(16) u32 lds_p[4][544];  // per-wave [16 q][34], reused per sub

  const int bid = blockIdx.x;
  const int split = bid & 7;
  const int dir = (bid >> 3) & 1;
  const int qt = bid >> 4;
  const int slab = dir * 8 + split;
  const int kvbase = split * 1024;

  const u16* Q = dir ? Qb1 : Qb0;
  const u16* K = dir ? Kb1 : Kb0;
  const u16* V = dir ? Vb1 : Vb0;

  const int t = threadIdx.x;
  const int w = t >> 6;
  const int lane = t & 63;
  const int g = lane >> 4;
  const int l16 = lane & 15;
  const int qblk = qt * 256 + w * 64;

  // ---- Q B-fragments: 4 q-subtiles x 2 k-chunks (pre-scaled by 1/8) ----
  short8 qa[4][2];
#pragma unroll
  for (int sub = 0; sub < 4; ++sub)
#pragma unroll
    for (int c = 0; c < 2; ++c)
      qa[sub][c] = *reinterpret_cast<const short8*>(
          Q + (size_t)(qblk + sub * 16 + l16) * 64 + 32 * c + 8 * g);

  f32x4 oacc[4][4];
#pragma unroll
  for (int sub = 0; sub < 4; ++sub)
#pragma unroll
    for (int db = 0; db < 4; ++db) oacc[sub][db] = f32x4{0.f, 0.f, 0.f, 0.f};
  float l_run[4] = {0.f, 0.f, 0.f, 0.f};

  const int kv0 = (t >> 4) << 2;
  const int d0 = (t & 15) << 2;
  ushort4 kh[4], vh[4];

#define LOADT(tile_)                                                          \
  {                                                                           \
    _Pragma("unroll") for (int j = 0; j < 4; ++j) {                           \
      const size_t off = ((size_t)(kvbase + (tile_)*64 + kv0 + j)) * 64 + d0; \
      kh[j] = *reinterpret_cast<const ushort4*>(K + off);                     \
      vh[j] = *reinterpret_cast<const ushort4*>(V + off);                     \
    }                                                                         \
  }

#define STORET()                                                              \
  {                                                                           \
    _Pragma("unroll") for (int j = 0; j < 4; ++j) {                           \
      const int row = kv0 + j;                                                \
      *reinterpret_cast<ushort4*>(                                            \
          &lds_k[(row * 64 + d0) ^ ((row & 7) << 3)]) = kh[j];                \
    }                                                                         \
    _Pragma("unroll") for (int i = 0; i < 4; ++i) {                           \
      const int row = d0 + i;                                                 \
      ushort4 vt;                                                             \
      vt.x = (&vh[0].x)[i];                                                   \
      vt.y = (&vh[1].x)[i];                                                   \
      vt.z = (&vh[2].x)[i];                                                   \
      vt.w = (&vh[3].x)[i];                                                   \
      *reinterpret_cast<ushort4*>(                                            \
          &lds_vt[(row * 64 + kv0) ^ (((row >> 1) & 7) << 3)]) = vt;          \
    }                                                                         \
  }

  LOADT(0);
  STORET();
  LOADT(1);
  asm volatile("s_waitcnt lgkmcnt(0)" ::: "memory");
  __builtin_amdgcn_s_barrier();
  asm volatile("" ::: "memory");

  for (int tile = 0; tile < 16; ++tile) {
    // ---- S^T = K Q for all 4 subs (K-fragment loaded once) ----
    f32x4 sacc[4][4];
#pragma unroll
    for (int sub = 0; sub < 4; ++sub)
#pragma unroll
      for (int kb = 0; kb < 4; ++kb) sacc[sub][kb] = f32x4{0.f, 0.f, 0.f, 0.f};
#pragma unroll
    for (int c = 0; c < 2; ++c) {
#pragma unroll
      for (int kb = 0; kb < 4; ++kb) {
        const int row = 16 * kb + l16;
        const int idx = (row * 64 + 32 * c + 8 * g) ^ ((row & 7) << 3);
        const short8 kfrag = *reinterpret_cast<const short8*>(&lds_k[idx]);
#pragma unroll
        for (int sub = 0; sub < 4; ++sub)
          sacc[sub][kb] = __builtin_amdgcn_mfma_f32_16x16x32_bf16(
              kfrag, qa[sub][c], sacc[sub][kb], 0, 0, 0);
      }
    }

    // ---- no-max softmax (__expf); per-sub P round-trip via reused buffer ----
    short8 pB[4][2];
#pragma unroll
    for (int sub = 0; sub < 4; ++sub) {
      float lsub = 0.f;
#pragma unroll
      for (int kb = 0; kb < 4; ++kb) {
        const float p0 = __expf(sacc[sub][kb][0]);
        const float p1 = __expf(sacc[sub][kb][1]);
        const float p2 = __expf(sacc[sub][kb][2]);
        const float p3 = __expf(sacc[sub][kb][3]);
        lsub += (p0 + p1) + (p2 + p3);
        u32 w0, w1;
        asm("v_cvt_pk_bf16_f32 %0, %1, %2" : "=v"(w0) : "v"(p0), "v"(p1));
        asm("v_cvt_pk_bf16_f32 %0, %1, %2" : "=v"(w1) : "v"(p2), "v"(p3));
        *reinterpret_cast<uint2*>(&lds_p[w][l16 * 34 + 8 * kb + 2 * g]) =
            make_uint2(w0, w1);
      }
      l_run[sub] += lsub;
      asm volatile("" ::: "memory");  // writes before reads (in-wave DS order)
#pragma unroll
      for (int c = 0; c < 2; ++c) {
        const int base = l16 * 34 + 16 * c + 4 * g;
        const uint2 a = *reinterpret_cast<const uint2*>(&lds_p[w][base]);
        const uint2 bb = *reinterpret_cast<const uint2*>(&lds_p[w][base + 2]);
        u32 q4[4] = {a.x, a.y, bb.x, bb.y};
        pB[sub][c] = __builtin_bit_cast(short8, *(ulonglong2*)q4);
      }
      asm volatile("" ::: "memory");  // reads before next sub's overwrite
    }

    // ---- O^T += V^T P^T (V-fragment loaded once, shared by 4 subs) ----
#pragma unroll
    for (int c = 0; c < 2; ++c) {
#pragma unroll
      for (int db = 0; db < 4; ++db) {
        const int row = 16 * db + l16;
        const int idx = (row * 64 + 32 * c + 8 * g) ^ (((row >> 1) & 7) << 3);
        const short8 vfrag = *reinterpret_cast<const short8*>(&lds_vt[idx]);
#pragma unroll
        for (int sub = 0; sub < 4; ++sub)
          oacc[sub][db] = __builtin_amdgcn_mfma_f32_16x16x32_bf16(
              vfrag, pB[sub][c], oacc[sub][db], 0, 0, 0);
      }
    }

    // ---- rotate single K/V buffer ----
    asm volatile("s_waitcnt lgkmcnt(0)" ::: "memory");
    __builtin_amdgcn_s_barrier();
    asm volatile("" ::: "memory");
    if (tile < 15) {
      STORET();
      if (tile < 14) LOADT(tile + 2);
    }
    asm volatile("s_waitcnt lgkmcnt(0)" ::: "memory");
    __builtin_amdgcn_s_barrier();
    asm volatile("" ::: "memory");
  }

  // ---- epilogue: bf16 unnormalized O + f32 l ----
  const size_t S = (size_t)8192 * 64;
#pragma unroll
  for (int sub = 0; sub < 4; ++sub) {
    const int q = qblk + sub * 16 + l16;
#pragma unroll
    for (int db = 0; db < 4; ++db) {
      u32 w0, w1;
      asm("v_cvt_pk_bf16_f32 %0, %1, %2"
          : "=v"(w0)
          : "v"(oacc[sub][db][0]), "v"(oacc[sub][db][1]));
      asm("v_cvt_pk_bf16_f32 %0, %1, %2"
          : "=v"(w1)
          : "v"(oacc[sub][db][2]), "v"(oacc[sub][db][3]));
      *reinterpret_cast<uint2*>(Opart + (size_t)slab * S + (size_t)q * 64 +
                                16 * db + 4 * g) = make_uint2(w0, w1);
    }
    float lv = l_run[sub];
    lv += __shfl_xor(lv, 16, 64);
    lv += __shfl_xor(lv, 32, 64);
    if (g == 0) lpart[slab * 8192 + q] = lv;
  }
#undef LOADT
#undef STORET
}

// ---------------- post (R9/R10/R11-proven body; merge of 8 splits) ----------------
__global__ __launch_bounds__(256) void post_kernel(
    const u16* __restrict__ Opart, const float* __restrict__ lpart,
    const float* __restrict__ nirF, const float* __restrict__ libsF,
    const float* __restrict__ ln1g, const float* __restrict__ ln1b,
    const float* __restrict__ fc1w, const float* __restrict__ fc1b,
    const float* __restrict__ ln2g, const float* __restrict__ ln2b,
    const float* __restrict__ fc2w, const float* __restrict__ fc2b,
    const float* __restrict__ ln0g, const float* __restrict__ ln0b,
    const float* __restrict__ gatew, const float* __restrict__ gateb,
    const float* __restrict__ ln3g, const float* __restrict__ ln3b,
    const float* __restrict__ fc3w, const float* __restrict__ fc3b,
    const float* __restrict__ ln4g, const float* __restrict__ ln4b,
    const float* __restrict__ fc4w, const float* __restrict__ fc4b,
    float* __restrict__ out) {
  __shared__ u16 FC1[4096], FC2[4096], FC3[2048];
  __shared__ u16 GW[8192];
  __shared__ float rbuf[4][128];
  const int t = threadIdx.x, w = t >> 6, lane = t & 63;
  const size_t S = (size_t)8192 * 64;
  for (int i = t; i < 4096; i += 256) {
    FC1[i] = f2bf(fc1w[i]);
    FC2[i] = f2bf(fc2w[i]);
  }
  for (int i = t; i < 2048; i += 256) FC3[i] = f2bf(fc3w[i]);
  for (int i = t; i < 8192; i += 256) GW[i] = f2bf(gatew[i]);
  __syncthreads();
#pragma unroll
  for (int rr = 0; rr < 2; ++rr) {
    const int r = blockIdx.x * 8 + rr * 4 + w;
    const size_t ro = (size_t)r * 64;

    // merge 8 KV-splits per direction (no-max: plain sums), bf16 partials
    float a1 = 0.f, a2 = 0.f, l1 = 0.f, l2 = 0.f;
#pragma unroll
    for (int s = 0; s < 8; ++s) {
      a1 += bf2f(Opart[(size_t)s * S + ro + lane]);
      a2 += bf2f(Opart[(size_t)(8 + s) * S + ro + lane]);
      l1 += lpart[s * 8192 + r];
      l2 += lpart[(8 + s) * 8192 + r];
    }
    a1 /= l1;  // attn_libs_to_nir
    a2 /= l2;  // attn_nir_to_libs

    const float nv = nirF[ro + lane], lv_ = libsF[ro + lane];

    // out1 = relu(LN(a2; ln1) @ fc1 + b) + libs
    float s1 = wave_sum64(a2), ss1 = wave_sum64(a2 * a2);
    float mean = s1 * (1.f / 64);
    float rstd = rsqrtf(ss1 * (1.f / 64) - mean * mean + LN_EPS);
    rbuf[w][lane] = (a2 - mean) * rstd * ln1g[lane] + ln1b[lane];
    __syncthreads();
    float o1 = fc1b[lane];
#pragma unroll 8
    for (int i = 0; i < 64; ++i)
      o1 = fmaf(rbuf[w][i], bf2f(FC1[i * 64 + lane]), o1);
    const float out1 = fmaxf(o1, 0.f) + lv_;
    __syncthreads();

    // out2 = relu(LN(a1; ln2) @ fc2 + b) + nir
    s1 = wave_sum64(a1);
    ss1 = wave_sum64(a1 * a1);
    mean = s1 * (1.f / 64);
    rstd = rsqrtf(ss1 * (1.f / 64) - mean * mean + LN_EPS);
    rbuf[w][lane] = (a1 - mean) * rstd * ln2g[lane] + ln2b[lane];
    __syncthreads();
    float o2 = fc2b[lane];
#pragma unroll 8
    for (int i = 0; i < 64; ++i)
      o2 = fmaf(rbuf[w][i], bf2f(FC2[i * 64 + lane]), o2);
    const float out2 = fmaxf(o2, 0.f) + nv;
    __syncthreads();

    // gate
    s1 = wave_sum64(out1 + out2);
    ss1 = wave_sum64(out1 * out1 + out2 * out2);
    mean = s1 * (1.f / 128);
    rstd = rsqrtf(ss1 * (1.f / 128) - mean * mean + LN_EPS);
    rbuf[w][lane] = (out1 - mean) * rstd * ln0g[lane] + ln0b[lane];
    rbuf[w][64 + lane] =
        (out2 - mean) * rstd * ln0g[64 + lane] + ln0b[64 + lane];
    __syncthreads();
    float gg = gateb[lane];
#pragma unroll 8
    for (int i = 0; i < 128; ++i)
      gg = fmaf(rbuf[w][i], bf2f(GW[i * 64 + lane]), gg);
    gg = 1.f / (1.f + __expf(-gg));
    const float fused = gg * out1 + (1.f - gg) * out2;
    __syncthreads();

    // head: LN -> fc3 -> relu -> LN -> fc4
    s1 = wave_sum64(fused);
    ss1 = wave_sum64(fused * fused);
    mean = s1 * (1.f / 64);
    rstd = rsqrtf(ss1 * (1.f / 64) - mean * mean + LN_EPS);
    rbuf[w][lane] = (fused - mean) * rstd * ln3g[lane] + ln3b[lane];
    __syncthreads();
    if (lane < 32) {
      float h = fc3b[lane];
#pragma unroll 8
      for (int i = 0; i < 64; ++i)
        h = fmaf(rbuf[w][i], bf2f(FC3[i * 32 + lane]), h);
      h = fmaxf(h, 0.f);
      const float hs = grp32_sum(h), hss = grp32_sum(h * h);
      const float hm = hs * (1.f / 32);
      const float hr = rsqrtf(hss * (1.f / 32) - hm * hm + LN_EPS);
      const float y4 = (h - hm) * hr * ln4g[lane] + ln4b[lane];
      const float part = grp32_sum(y4 * fc4w[lane]);
      if (lane == 0) out[r] = part + fc4b[0];
    }
    __syncthreads();
  }
}

extern "C" void kernel_launch(void* const* d_in, const int* in_sizes, int n_in,
                              void* d_out, int out_size, void* d_ws,
                              size_t ws_size, hipStream_t stream) {
  const float* nir_data = (const float*)d_in[0];
  const float* libs_data = (const float*)d_in[1];
  const float* nir_ln_g = (const float*)d_in[2];
  const float* nir_ln_b = (const float*)d_in[3];
  const float* nir_w = (const float*)d_in[4];
  const float* nir_b = (const float*)d_in[5];
  const float* libs_ln_g = (const float*)d_in[6];
  const float* libs_ln_b = (const float*)d_in[7];
  const float* libs_w = (const float*)d_in[8];
  const float* libs_b = (const float*)d_in[9];
  const float* q_ln_w = (const float*)d_in[10];
  const float* q_ln_b = (const float*)d_in[11];
  const float* k_ln_w = (const float*)d_in[12];
  const float* k_ln_b = (const float*)d_in[13];
  const float* v_ln_w = (const float*)d_in[14];
  const float* v_ln_b = (const float*)d_in[15];
  const float* q_nl_w = (const float*)d_in[16];
  const float* q_nl_b = (const float*)d_in[17];
  const float* k_nl_w = (const float*)d_in[18];
  const float* k_nl_b = (const float*)d_in[19];
  const float* v_nl_w = (const float*)d_in[20];
  const float* v_nl_b = (const float*)d_in[21];
  const float* ln1_g = (const float*)d_in[22];
  const float* ln1_b = (const float*)d_in[23];
  const float* fc1_w = (const float*)d_in[24];
  const float* fc1_b = (const float*)d_in[25];
  const float* ln2_g = (const float*)d_in[26];
  const float* ln2_b = (const float*)d_in[27];
  const float* fc2_w = (const float*)d_in[28];
  const float* fc2_b = (const float*)d_in[29];
  const float* ln0_g = (const float*)d_in[30];
  const float* ln0_b = (const float*)d_in[31];
  const float* gate_w = (const float*)d_in[32];
  const float* gate_b = (const float*)d_in[33];
  const float* ln3_g = (const float*)d_in[34];
  const float* ln3_b = (const float*)d_in[35];
  const float* fc3_w = (const float*)d_in[36];
  const float* fc3_b = (const float*)d_in[37];
  const float* ln4_g = (const float*)d_in[38];
  const float* ln4_b = (const float*)d_in[39];
  const float* fc4_w = (const float*)d_in[40];
  const float* fc4_b = (const float*)d_in[41];

  const size_t S = (size_t)8192 * 64;
  u16* ub = (u16*)d_ws;
  u16* Qb_nir = ub + 0 * S;
  u16* Kb_nir = ub + 1 * S;
  u16* Vb_nir = ub + 2 * S;
  u16* Qb_libs = ub + 3 * S;
  u16* Kb_libs = ub + 4 * S;
  u16* Vb_libs = ub + 5 * S;
  u16* OpartU = ub + 6 * S;  // 16 slabs bf16 (2 dirs x 8 splits)
  float* fp = (float*)(ub + 22 * S);
  float* f_nir = fp + 0 * S;
  float* f_libs = fp + 1 * S;
  float* lpart = fp + 2 * S;  // 16 x 8192

  extract_fused_kernel<<<2048, 256, 0, stream>>>(
      nir_data, libs_data, nir_ln_g, nir_ln_b, nir_w, nir_b, libs_ln_g,
      libs_ln_b, libs_w, libs_b, q_ln_w, q_ln_b, k_ln_w, k_ln_b, v_ln_w,
      v_ln_b, q_nl_w, q_nl_b, k_nl_w, k_nl_b, v_nl_w, v_nl_b, f_nir, f_libs,
      Qb_nir, Kb_nir, Vb_nir, Qb_libs, Kb_libs, Vb_libs);

  // dir0: Q_libs x K/V_nir ; dir1: Q_nir x K/V_libs
  attn_mfma_kernel<<<512, 256, 0, stream>>>(Qb_libs, Kb_nir, Vb_nir, Qb_nir,
                                            Kb_libs, Vb_libs, OpartU, lpart);

  post_kernel<<<1024, 256, 0, stream>>>(
      OpartU, lpart, f_nir, f_libs, ln1_g, ln1_b, fc1_w, fc1_b, ln2_g, ln2_b,
      fc2_w, fc2_b, ln0_g, ln0_b, gate_w, gate_b, ln3_g, ln3_b, fc3_w, fc3_b,
      ln4_g, ln4_b, fc4_w, fc4_b, (float*)d_out);
}